// Round 1
// baseline (3158.346 us; speedup 1.0000x reference)
//
#include <hip/hip_runtime.h>
#include <math.h>

#define BSZ  2
#define SEQN 4096
#define HD   768
#define NL   8921

#define BM 64
#define BN 64
#define BK 16
#define PAD 4

// ---------------------------------------------------------------------------
// NT GEMM: C = op(A * B^T). A: MxK row-major, B: NxK row-major, C: MxN row-major.
// Per-batch strides via blockIdx.z. Optional elementwise tanh on output.
// 256 threads, 64x64 tile, 4x4 per thread, BK=16.
// ---------------------------------------------------------------------------
template<bool TANH>
__global__ __launch_bounds__(256)
void nt_gemm(const float* __restrict__ A, const float* __restrict__ B,
             float* __restrict__ C, int M, int N, int K,
             long long sA, long long sB, long long sC)
{
    A += (long long)blockIdx.z * sA;
    B += (long long)blockIdx.z * sB;
    C += (long long)blockIdx.z * sC;

    __shared__ __align__(16) float As[BK][BM + PAD];
    __shared__ __align__(16) float Bs[BK][BN + PAD];

    const int t  = threadIdx.x;
    const int m0 = blockIdx.y * BM;
    const int n0 = blockIdx.x * BN;

    const int tx = t & 15;        // 0..15 -> n
    const int ty = t >> 4;        // 0..15 -> m
    const int lr = t >> 2;        // 0..63  staging row
    const int lk = (t & 3) * 4;   // 0,4,8,12 staging k offset

    float acc[4][4] = {};

    for (int kt = 0; kt < K; kt += BK) {
        {
            float4 v = make_float4(0.f, 0.f, 0.f, 0.f);
            int m = m0 + lr;
            if (m < M) v = *(const float4*)(A + (long long)m * K + kt + lk);
            As[lk + 0][lr] = v.x; As[lk + 1][lr] = v.y;
            As[lk + 2][lr] = v.z; As[lk + 3][lr] = v.w;
        }
        {
            float4 v = make_float4(0.f, 0.f, 0.f, 0.f);
            int n = n0 + lr;
            if (n < N) v = *(const float4*)(B + (long long)n * K + kt + lk);
            Bs[lk + 0][lr] = v.x; Bs[lk + 1][lr] = v.y;
            Bs[lk + 2][lr] = v.z; Bs[lk + 3][lr] = v.w;
        }
        __syncthreads();
        #pragma unroll
        for (int k = 0; k < BK; ++k) {
            float4 a = *(const float4*)(&As[k][ty * 4]);
            float4 b = *(const float4*)(&Bs[k][tx * 4]);
            float av[4] = {a.x, a.y, a.z, a.w};
            float bv[4] = {b.x, b.y, b.z, b.w};
            #pragma unroll
            for (int i = 0; i < 4; ++i)
                #pragma unroll
                for (int j = 0; j < 4; ++j)
                    acc[i][j] = fmaf(av[i], bv[j], acc[i][j]);
        }
        __syncthreads();
    }

    #pragma unroll
    for (int i = 0; i < 4; ++i) {
        int m = m0 + ty * 4 + i;
        if (m < M) {
            float4 r;
            r.x = TANH ? tanhf(acc[i][0]) : acc[i][0];
            r.y = TANH ? tanhf(acc[i][1]) : acc[i][1];
            r.z = TANH ? tanhf(acc[i][2]) : acc[i][2];
            r.w = TANH ? tanhf(acc[i][3]) : acc[i][3];
            *(float4*)(C + (long long)m * N + n0 + tx * 4) = r;
        }
    }
}

// ---------------------------------------------------------------------------
// NN GEMM: C = A * B. A: MxK row-major, B: KxN row-major, C: MxN row-major.
// ---------------------------------------------------------------------------
__global__ __launch_bounds__(256)
void nn_gemm(const float* __restrict__ A, const float* __restrict__ B,
             float* __restrict__ C, int M, int N, int K,
             long long sA, long long sB, long long sC)
{
    A += (long long)blockIdx.z * sA;
    B += (long long)blockIdx.z * sB;
    C += (long long)blockIdx.z * sC;

    __shared__ __align__(16) float As[BK][BM + PAD];
    __shared__ __align__(16) float Bs[BK][BN + PAD];

    const int t  = threadIdx.x;
    const int m0 = blockIdx.y * BM;
    const int n0 = blockIdx.x * BN;

    const int tx = t & 15;
    const int ty = t >> 4;
    const int lr = t >> 2;        // A staging row 0..63
    const int lk = (t & 3) * 4;   // A staging k offset
    const int kr = t >> 4;        // B staging k row 0..15
    const int cq = (t & 15) * 4;  // B staging col offset

    float acc[4][4] = {};

    for (int kt = 0; kt < K; kt += BK) {
        {
            float4 v = make_float4(0.f, 0.f, 0.f, 0.f);
            int m = m0 + lr;
            if (m < M) v = *(const float4*)(A + (long long)m * K + kt + lk);
            As[lk + 0][lr] = v.x; As[lk + 1][lr] = v.y;
            As[lk + 2][lr] = v.z; As[lk + 3][lr] = v.w;
        }
        {
            float4 v = *(const float4*)(B + (long long)(kt + kr) * N + n0 + cq);
            *(float4*)(&Bs[kr][cq]) = v;
        }
        __syncthreads();
        #pragma unroll
        for (int k = 0; k < BK; ++k) {
            float4 a = *(const float4*)(&As[k][ty * 4]);
            float4 b = *(const float4*)(&Bs[k][tx * 4]);
            float av[4] = {a.x, a.y, a.z, a.w};
            float bv[4] = {b.x, b.y, b.z, b.w};
            #pragma unroll
            for (int i = 0; i < 4; ++i)
                #pragma unroll
                for (int j = 0; j < 4; ++j)
                    acc[i][j] = fmaf(av[i], bv[j], acc[i][j]);
        }
        __syncthreads();
    }

    #pragma unroll
    for (int i = 0; i < 4; ++i) {
        int m = m0 + ty * 4 + i;
        if (m < M) {
            float4 r = make_float4(acc[i][0], acc[i][1], acc[i][2], acc[i][3]);
            *(float4*)(C + (long long)m * N + n0 + tx * 4) = r;
        }
    }
}

// ---------------------------------------------------------------------------
// Row softmax over 4096 contiguous elements, in place. One block (256 thr) per row.
// ---------------------------------------------------------------------------
__global__ __launch_bounds__(256)
void softmax_rows(float* __restrict__ data)
{
    const long long row = blockIdx.x;
    float* p = data + row * (long long)SEQN;
    const int t = threadIdx.x;

    float4 v[4];
    float vmax = -INFINITY;
    #pragma unroll
    for (int i = 0; i < 4; ++i) {
        v[i] = ((const float4*)p)[t + 256 * i];
        vmax = fmaxf(vmax, fmaxf(fmaxf(v[i].x, v[i].y), fmaxf(v[i].z, v[i].w)));
    }
    #pragma unroll
    for (int off = 32; off > 0; off >>= 1)
        vmax = fmaxf(vmax, __shfl_xor(vmax, off));

    __shared__ float redmax[4];
    __shared__ float redsum[4];
    if ((t & 63) == 0) redmax[t >> 6] = vmax;
    __syncthreads();
    vmax = fmaxf(fmaxf(redmax[0], redmax[1]), fmaxf(redmax[2], redmax[3]));

    float sum = 0.f;
    #pragma unroll
    for (int i = 0; i < 4; ++i) {
        v[i].x = expf(v[i].x - vmax);
        v[i].y = expf(v[i].y - vmax);
        v[i].z = expf(v[i].z - vmax);
        v[i].w = expf(v[i].w - vmax);
        sum += (v[i].x + v[i].y) + (v[i].z + v[i].w);
    }
    #pragma unroll
    for (int off = 32; off > 0; off >>= 1)
        sum += __shfl_xor(sum, off);
    if ((t & 63) == 0) redsum[t >> 6] = sum;
    __syncthreads();
    sum = (redsum[0] + redsum[1]) + (redsum[2] + redsum[3]);

    const float inv = 1.0f / sum;
    #pragma unroll
    for (int i = 0; i < 4; ++i) {
        v[i].x *= inv; v[i].y *= inv; v[i].z *= inv; v[i].w *= inv;
        ((float4*)p)[t + 256 * i] = v[i];
    }
}

// ---------------------------------------------------------------------------
extern "C" void kernel_launch(void* const* d_in, const int* in_sizes, int n_in,
                              void* d_out, int out_size, void* d_ws, size_t ws_size,
                              hipStream_t stream)
{
    const float* code = (const float*)d_in[0];   // (L, H)
    const float* text = (const float*)d_in[1];   // (BS, SEQ, H)
    // d_in[2]: attention_mask — unused by the reference computation
    const float* Wm   = (const float*)d_in[3];   // (H, H)

    float* att  = (float*)d_out;                          // (BS, L, SEQ)
    float* wout = att + (long long)BSZ * NL * SEQN;       // (BS, L, H)
    // proj (BS*SEQ, H) = 6.29M floats temporarily lives in the wout region
    // (13.7M floats): written by K1, consumed by K2, overwritten by K4.
    float* proj = wout;

    // 1) proj = tanh(text @ W^T): M = BS*SEQ = 8192, N = H, K = H
    {
        dim3 g(HD / BN, (BSZ * SEQN) / BM, 1);
        hipLaunchKernelGGL((nt_gemm<true>), g, dim3(256), 0, stream,
                           text, Wm, proj, BSZ * SEQN, HD, HD, 0LL, 0LL, 0LL);
    }
    // 2) per batch: att_b = code @ proj_b^T : M = L, N = SEQ, K = H
    {
        dim3 g(SEQN / BN, (NL + BM - 1) / BM, BSZ);
        hipLaunchKernelGGL((nt_gemm<false>), g, dim3(256), 0, stream,
                           code, proj, att, NL, SEQN, HD,
                           0LL, (long long)SEQN * HD, (long long)NL * SEQN);
    }
    // 3) softmax over seq (last axis of att), in place
    {
        dim3 g(BSZ * NL);
        hipLaunchKernelGGL(softmax_rows, g, dim3(256), 0, stream, att);
    }
    // 4) per batch: wout_b = att_b @ text_b : M = L, N = H, K = SEQ
    {
        dim3 g(HD / BN, (NL + BM - 1) / BM, BSZ);
        hipLaunchKernelGGL(nn_gemm, g, dim3(256), 0, stream,
                           att, text, wout, NL, HD, SEQN,
                           (long long)NL * SEQN, (long long)SEQN * HD,
                           (long long)NL * HD);
    }
}

// Round 2
// 627.892 us; speedup vs baseline: 5.0301x; 5.0301x over previous
//
#include <hip/hip_runtime.h>
#include <math.h>

#define BSZ  2
#define SEQN 4096
#define HD   768
#define NL   8921

typedef _Float16 f16;
typedef f16   f16x8 __attribute__((ext_vector_type(8)));
typedef float f32x4 __attribute__((ext_vector_type(4)));

#define GPTR(p) ((const __attribute__((address_space(1))) void*)(p))
#define LPTR(p) ((__attribute__((address_space(3))) void*)(p))

// ===========================================================================
// MFMA NT GEMM: C = op(A * B^T). A: M x K (row-major, k contiguous),
// B: N x K (row-major, k contiguous), C: M x N row-major fp32 (or tanh->f16).
// Tile 128x128, BK=32, 256 threads = 4 waves (2x2), wave tile 64x64,
// mfma_f32_16x16x32_f16, fp32 accumulate.
// SA/SB: 1 = source already f16 (stage via global_load_lds),
//        0 = source fp32 (register-stage + convert).
// OUTMODE: 0 = fp32 store, 1 = tanh -> f16 store.
// ===========================================================================
template<int S16>
__device__ inline void stage_tile(const void* srcv, int ldk, int row0, int rowMax,
                                  int kt, f16* dst, int t, int lane, int wv)
{
    if constexpr (S16) {
        const f16* src = (const f16*)srcv;
        #pragma unroll
        for (int j = 0; j < 2; ++j) {
            int r = wv * 32 + j * 16 + (lane >> 2);
            int row = row0 + r; if (row > rowMax) row = rowMax;
            const f16* g = src + (long long)row * ldk + kt + (lane & 3) * 8;
            f16* l = dst + (wv * 32 + j * 16) * 32;   // wave-uniform base
            __builtin_amdgcn_global_load_lds(GPTR(g), LPTR(l), 16, 0, 0);
        }
    } else {
        const float* src = (const float*)srcv;
        int r  = t >> 1;             // 0..127
        int kq = (t & 1) * 16;       // element offset within BK=32
        int row = row0 + r; if (row > rowMax) row = rowMax;
        const float* g = src + (long long)row * ldk + kt + kq;
        float4 v0 = ((const float4*)g)[0];
        float4 v1 = ((const float4*)g)[1];
        float4 v2 = ((const float4*)g)[2];
        float4 v3 = ((const float4*)g)[3];
        f16x8 h0, h1;
        h0[0]=(f16)v0.x; h0[1]=(f16)v0.y; h0[2]=(f16)v0.z; h0[3]=(f16)v0.w;
        h0[4]=(f16)v1.x; h0[5]=(f16)v1.y; h0[6]=(f16)v1.z; h0[7]=(f16)v1.w;
        h1[0]=(f16)v2.x; h1[1]=(f16)v2.y; h1[2]=(f16)v2.z; h1[3]=(f16)v2.w;
        h1[4]=(f16)v3.x; h1[5]=(f16)v3.y; h1[6]=(f16)v3.z; h1[7]=(f16)v3.w;
        *(f16x8*)&dst[r * 32 + kq]     = h0;
        *(f16x8*)&dst[r * 32 + kq + 8] = h1;
    }
}

template<int SA, int SB, int OUTMODE>
__global__ __launch_bounds__(256)
void mfma_nt(const void* __restrict__ A, const void* __restrict__ B,
             void* __restrict__ C, int M, int N, int K,
             long long sA, long long sB, long long sC, int ldA, int ldB)
{
    const char* Ab = (const char*)A + (long long)blockIdx.z * sA * (SA ? 2 : 4);
    const char* Bb = (const char*)B + (long long)blockIdx.z * sB * (SB ? 2 : 4);

    __shared__ __align__(16) f16 As[128 * 32];
    __shared__ __align__(16) f16 Bs[128 * 32];

    const int t    = threadIdx.x;
    const int lane = t & 63;
    const int wv   = t >> 6;
    const int wr   = wv >> 1;
    const int wc   = wv & 1;
    const int m0   = blockIdx.y * 128;
    const int n0   = blockIdx.x * 128;

    f32x4 acc[4][4] = {};

    for (int kt = 0; kt < K; kt += 32) {
        stage_tile<SA>(Ab, ldA, m0, M - 1, kt, As, t, lane, wv);
        stage_tile<SB>(Bb, ldB, n0, N - 1, kt, Bs, t, lane, wv);
        __syncthreads();

        f16x8 af[4], bf[4];
        const int kc = (lane >> 4) * 8;
        const int rl = lane & 15;
        #pragma unroll
        for (int i = 0; i < 4; ++i)
            af[i] = *(const f16x8*)&As[(wr * 64 + i * 16 + rl) * 32 + kc];
        #pragma unroll
        for (int j = 0; j < 4; ++j)
            bf[j] = *(const f16x8*)&Bs[(wc * 64 + j * 16 + rl) * 32 + kc];

        #pragma unroll
        for (int i = 0; i < 4; ++i)
            #pragma unroll
            for (int j = 0; j < 4; ++j)
                acc[i][j] = __builtin_amdgcn_mfma_f32_16x16x32_f16(af[i], bf[j], acc[i][j], 0, 0, 0);
        __syncthreads();
    }

    const int rquad = (lane >> 4) * 4;
    const int rcol  = lane & 15;
    #pragma unroll
    for (int i = 0; i < 4; ++i) {
        #pragma unroll
        for (int j = 0; j < 4; ++j) {
            #pragma unroll
            for (int r = 0; r < 4; ++r) {
                int row = m0 + wr * 64 + i * 16 + rquad + r;
                int col = n0 + wc * 64 + j * 16 + rcol;
                if (row < M) {
                    if constexpr (OUTMODE == 1)
                        ((f16*)C)[(long long)row * N + col] = (f16)tanhf(acc[i][j][r]);
                    else
                        ((float*)C + (long long)blockIdx.z * sC)[(long long)row * N + col] = acc[i][j][r];
                }
            }
        }
    }
}

// ===========================================================================
// fp32 -> f16 convert (n divisible by 4)
// ===========================================================================
__global__ __launch_bounds__(256)
void cvt_f32_f16(const float* __restrict__ in, f16* __restrict__ out, long long n4)
{
    long long i = (long long)blockIdx.x * 256 + threadIdx.x;
    if (i < n4) {
        float4 v = ((const float4*)in)[i];
        f16 h[4] = {(f16)v.x, (f16)v.y, (f16)v.z, (f16)v.w};
        *(uint2*)&out[i * 4] = *(uint2*)h;
    }
}

// ===========================================================================
// text (BS,SEQ,HD) fp32 -> textT (BS,HD,SEQ) f16
// ===========================================================================
__global__ __launch_bounds__(256)
void transpose_f16(const float* __restrict__ in, f16* __restrict__ out)
{
    __shared__ float tile[32][33];
    const int b  = blockIdx.z;
    const int h0 = blockIdx.x * 32, s0 = blockIdx.y * 32;
    in  += (long long)b * SEQN * HD;
    out += (long long)b * HD * SEQN;
    const int tx = threadIdx.x & 31, ty = threadIdx.x >> 5;  // 32 x 8
    #pragma unroll
    for (int i = ty; i < 32; i += 8)
        tile[i][tx] = in[(long long)(s0 + i) * HD + h0 + tx];
    __syncthreads();
    #pragma unroll
    for (int i = ty; i < 32; i += 8)
        out[(long long)(h0 + i) * SEQN + s0 + tx] = (f16)tile[tx][i];
}

// ===========================================================================
// Row softmax over 4096 contiguous fp32, in place; optional f16 copy.
// ===========================================================================
template<bool W16>
__global__ __launch_bounds__(256)
void softmax_rows(float* __restrict__ data, f16* __restrict__ data16)
{
    const long long row = blockIdx.x;
    float* p = data + row * (long long)SEQN;
    const int t = threadIdx.x;

    float4 v[4];
    float vmax = -INFINITY;
    #pragma unroll
    for (int i = 0; i < 4; ++i) {
        v[i] = ((const float4*)p)[t + 256 * i];
        vmax = fmaxf(vmax, fmaxf(fmaxf(v[i].x, v[i].y), fmaxf(v[i].z, v[i].w)));
    }
    #pragma unroll
    for (int off = 32; off > 0; off >>= 1)
        vmax = fmaxf(vmax, __shfl_xor(vmax, off));

    __shared__ float redmax[4];
    __shared__ float redsum[4];
    if ((t & 63) == 0) redmax[t >> 6] = vmax;
    __syncthreads();
    vmax = fmaxf(fmaxf(redmax[0], redmax[1]), fmaxf(redmax[2], redmax[3]));

    float sum = 0.f;
    #pragma unroll
    for (int i = 0; i < 4; ++i) {
        v[i].x = expf(v[i].x - vmax);
        v[i].y = expf(v[i].y - vmax);
        v[i].z = expf(v[i].z - vmax);
        v[i].w = expf(v[i].w - vmax);
        sum += (v[i].x + v[i].y) + (v[i].z + v[i].w);
    }
    #pragma unroll
    for (int off = 32; off > 0; off >>= 1)
        sum += __shfl_xor(sum, off);
    if ((t & 63) == 0) redsum[t >> 6] = sum;
    __syncthreads();
    sum = (redsum[0] + redsum[1]) + (redsum[2] + redsum[3]);

    const float inv = 1.0f / sum;
    #pragma unroll
    for (int i = 0; i < 4; ++i) {
        v[i].x *= inv; v[i].y *= inv; v[i].z *= inv; v[i].w *= inv;
        ((float4*)p)[t + 256 * i] = v[i];
        if constexpr (W16) {
            f16 h[4] = {(f16)v[i].x, (f16)v[i].y, (f16)v[i].z, (f16)v[i].w};
            *(uint2*)&data16[row * (long long)SEQN + (t + 256 * i) * 4] = *(uint2*)h;
        }
    }
}

// ===========================================================================
// Tier-C fallback (fp32 vector pipeline from round 1) — used only if d_ws
// is too small for the f16 operand buffers.
// ===========================================================================
#define BMF 64
#define BNF 64
#define BKF 16
#define PADF 4

template<bool TANH>
__global__ __launch_bounds__(256)
void nt_gemm(const float* __restrict__ A, const float* __restrict__ B,
             float* __restrict__ C, int M, int N, int K,
             long long sA, long long sB, long long sC)
{
    A += (long long)blockIdx.z * sA;
    B += (long long)blockIdx.z * sB;
    C += (long long)blockIdx.z * sC;
    __shared__ __align__(16) float As[BKF][BMF + PADF];
    __shared__ __align__(16) float Bs[BKF][BNF + PADF];
    const int t = threadIdx.x;
    const int m0 = blockIdx.y * BMF, n0 = blockIdx.x * BNF;
    const int tx = t & 15, ty = t >> 4, lr = t >> 2, lk = (t & 3) * 4;
    float acc[4][4] = {};
    for (int kt = 0; kt < K; kt += BKF) {
        {
            float4 v = make_float4(0.f, 0.f, 0.f, 0.f);
            int m = m0 + lr;
            if (m < M) v = *(const float4*)(A + (long long)m * K + kt + lk);
            As[lk+0][lr]=v.x; As[lk+1][lr]=v.y; As[lk+2][lr]=v.z; As[lk+3][lr]=v.w;
        }
        {
            float4 v = make_float4(0.f, 0.f, 0.f, 0.f);
            int n = n0 + lr;
            if (n < N) v = *(const float4*)(B + (long long)n * K + kt + lk);
            Bs[lk+0][lr]=v.x; Bs[lk+1][lr]=v.y; Bs[lk+2][lr]=v.z; Bs[lk+3][lr]=v.w;
        }
        __syncthreads();
        #pragma unroll
        for (int k = 0; k < BKF; ++k) {
            float4 a = *(const float4*)(&As[k][ty * 4]);
            float4 b = *(const float4*)(&Bs[k][tx * 4]);
            float av[4]={a.x,a.y,a.z,a.w}, bv[4]={b.x,b.y,b.z,b.w};
            #pragma unroll
            for (int i = 0; i < 4; ++i)
                #pragma unroll
                for (int j = 0; j < 4; ++j)
                    acc[i][j] = fmaf(av[i], bv[j], acc[i][j]);
        }
        __syncthreads();
    }
    #pragma unroll
    for (int i = 0; i < 4; ++i) {
        int m = m0 + ty * 4 + i;
        if (m < M) {
            float4 r;
            r.x = TANH ? tanhf(acc[i][0]) : acc[i][0];
            r.y = TANH ? tanhf(acc[i][1]) : acc[i][1];
            r.z = TANH ? tanhf(acc[i][2]) : acc[i][2];
            r.w = TANH ? tanhf(acc[i][3]) : acc[i][3];
            *(float4*)(C + (long long)m * N + n0 + tx * 4) = r;
        }
    }
}

__global__ __launch_bounds__(256)
void nn_gemm(const float* __restrict__ A, const float* __restrict__ B,
             float* __restrict__ C, int M, int N, int K,
             long long sA, long long sB, long long sC)
{
    A += (long long)blockIdx.z * sA;
    B += (long long)blockIdx.z * sB;
    C += (long long)blockIdx.z * sC;
    __shared__ __align__(16) float As[BKF][BMF + PADF];
    __shared__ __align__(16) float Bs[BKF][BNF + PADF];
    const int t = threadIdx.x;
    const int m0 = blockIdx.y * BMF, n0 = blockIdx.x * BNF;
    const int tx = t & 15, ty = t >> 4, lr = t >> 2, lk = (t & 3) * 4;
    const int kr = t >> 4, cq = (t & 15) * 4;
    float acc[4][4] = {};
    for (int kt = 0; kt < K; kt += BKF) {
        {
            float4 v = make_float4(0.f, 0.f, 0.f, 0.f);
            int m = m0 + lr;
            if (m < M) v = *(const float4*)(A + (long long)m * K + kt + lk);
            As[lk+0][lr]=v.x; As[lk+1][lr]=v.y; As[lk+2][lr]=v.z; As[lk+3][lr]=v.w;
        }
        {
            float4 v = *(const float4*)(B + (long long)(kt + kr) * N + n0 + cq);
            *(float4*)(&Bs[kr][cq]) = v;
        }
        __syncthreads();
        #pragma unroll
        for (int k = 0; k < BKF; ++k) {
            float4 a = *(const float4*)(&As[k][ty * 4]);
            float4 b = *(const float4*)(&Bs[k][tx * 4]);
            float av[4]={a.x,a.y,a.z,a.w}, bv[4]={b.x,b.y,b.z,b.w};
            #pragma unroll
            for (int i = 0; i < 4; ++i)
                #pragma unroll
                for (int j = 0; j < 4; ++j)
                    acc[i][j] = fmaf(av[i], bv[j], acc[i][j]);
        }
        __syncthreads();
    }
    #pragma unroll
    for (int i = 0; i < 4; ++i) {
        int m = m0 + ty * 4 + i;
        if (m < M)
            *(float4*)(C + (long long)m * N + n0 + tx * 4) =
                make_float4(acc[i][0], acc[i][1], acc[i][2], acc[i][3]);
    }
}

// ===========================================================================
extern "C" void kernel_launch(void* const* d_in, const int* in_sizes, int n_in,
                              void* d_out, int out_size, void* d_ws, size_t ws_size,
                              hipStream_t stream)
{
    const float* code = (const float*)d_in[0];   // (L, H)
    const float* text = (const float*)d_in[1];   // (BS, SEQ, H)
    const float* Wm   = (const float*)d_in[3];   // (H, H)

    float* att  = (float*)d_out;                          // (BS, L, SEQ)
    float* wout = att + (long long)BSZ * NL * SEQN;       // (BS, L, H)

    // ws layout (f16 elements)
    const long long n_code  = (long long)NL * HD;          // 6,851,328
    const long long n_proj  = (long long)BSZ * SEQN * HD;  // 6,291,456
    const long long n_textT = (long long)BSZ * HD * SEQN;  // 6,291,456
    const long long n_att   = (long long)BSZ * NL * SEQN;  // 73,080,832
    const size_t base_bytes = (size_t)(n_code + n_proj + n_textT) * 2;
    const size_t full_bytes = base_bytes + (size_t)n_att * 2;

    if (ws_size < base_bytes) {
        // ---- Tier C: fp32 fallback ----
        float* proj = wout;  // transient, overwritten by step 4
        dim3 g1(HD / BNF, (BSZ * SEQN) / BMF, 1);
        hipLaunchKernelGGL((nt_gemm<true>), g1, dim3(256), 0, stream,
                           text, Wm, proj, BSZ * SEQN, HD, HD, 0LL, 0LL, 0LL);
        dim3 g2(SEQN / BNF, (NL + BMF - 1) / BMF, BSZ);
        hipLaunchKernelGGL((nt_gemm<false>), g2, dim3(256), 0, stream,
                           code, proj, att, NL, SEQN, HD,
                           0LL, (long long)SEQN * HD, (long long)NL * SEQN);
        hipLaunchKernelGGL((softmax_rows<false>), dim3(BSZ * NL), dim3(256), 0, stream, att, (f16*)nullptr);
        dim3 g4(HD / BNF, (NL + BMF - 1) / BMF, BSZ);
        hipLaunchKernelGGL(nn_gemm, g4, dim3(256), 0, stream,
                           att, text, wout, NL, HD, SEQN,
                           (long long)NL * SEQN, (long long)SEQN * HD, (long long)NL * HD);
        return;
    }

    f16* code_h  = (f16*)d_ws;
    f16* proj_h  = code_h + n_code;
    f16* textT_h = proj_h + n_proj;
    f16* att_h   = textT_h + n_textT;
    const bool has_att16 = ws_size >= full_bytes;

    // 0a) code -> f16
    {
        long long n4 = n_code / 4;
        hipLaunchKernelGGL(cvt_f32_f16, dim3((unsigned)((n4 + 255) / 256)), dim3(256), 0, stream,
                           code, code_h, n4);
    }
    // 0b) text -> textT f16 (BS, HD, SEQN)
    {
        dim3 g(HD / 32, SEQN / 32, BSZ);
        hipLaunchKernelGGL(transpose_f16, g, dim3(256), 0, stream, text, textT_h);
    }
    // 1) proj_h = tanh(text @ W^T) as f16: M=8192, N=768, K=768  [fp32 sources]
    {
        dim3 g(HD / 128, (BSZ * SEQN) / 128, 1);
        hipLaunchKernelGGL((mfma_nt<0, 0, 1>), g, dim3(256), 0, stream,
                           text, Wm, proj_h, BSZ * SEQN, HD, HD, 0LL, 0LL, 0LL, HD, HD);
    }
    // 2) att_b = code @ proj_b^T : M=8921(L), N=4096(SEQ), K=768  [f16 sources]
    {
        dim3 g(SEQN / 128, (NL + 127) / 128, BSZ);
        hipLaunchKernelGGL((mfma_nt<1, 1, 0>), g, dim3(256), 0, stream,
                           code_h, proj_h, att, NL, SEQN, HD,
                           0LL, (long long)SEQN * HD, (long long)NL * SEQN, HD, HD);
    }
    // 3) softmax over seq (in place); optional f16 copy for step 4
    if (has_att16)
        hipLaunchKernelGGL((softmax_rows<true>), dim3(BSZ * NL), dim3(256), 0, stream, att, att_h);
    else
        hipLaunchKernelGGL((softmax_rows<false>), dim3(BSZ * NL), dim3(256), 0, stream, att, (f16*)nullptr);
    // 4) wout_b = att_b @ textT_b^T : M=8921(L), N=768(H), K=4096(SEQ)
    {
        dim3 g(HD / 128, (NL + 127) / 128, BSZ);
        if (has_att16)
            hipLaunchKernelGGL((mfma_nt<1, 1, 0>), g, dim3(256), 0, stream,
                               att_h, textT_h, wout, NL, HD, SEQN,
                               (long long)NL * SEQN, (long long)HD * SEQN, (long long)NL * HD,
                               SEQN, SEQN);
        else
            hipLaunchKernelGGL((mfma_nt<0, 1, 0>), g, dim3(256), 0, stream,
                               att, textT_h, wout, NL, HD, SEQN,
                               (long long)NL * SEQN, (long long)HD * SEQN, (long long)NL * HD,
                               SEQN, SEQN);
    }
}

// Round 3
// 481.795 us; speedup vs baseline: 6.5554x; 1.3032x over previous
//
#include <hip/hip_runtime.h>
#include <math.h>

#define BSZ  2
#define SEQN 4096
#define HD   768
#define NL   8921

typedef _Float16 f16;
typedef f16   f16x8 __attribute__((ext_vector_type(8)));
typedef float f32x4 __attribute__((ext_vector_type(4)));

#define GPTR(p) ((const __attribute__((address_space(1))) void*)(p))
#define LPTR(p) ((__attribute__((address_space(3))) void*)(p))

// ===========================================================================
// 8-phase 256x256 NT GEMM (f16 in, fp32 out), BK=64, 8 waves (2Mx4N),
// mfma_f32_16x16x32_f16. LDS [2 dbuf][A/B][2 ksub][256 rows][32 k] = 128 KiB.
// Schedule per K-tile (4 phases), verified region ledger:
//   p1: DS A-ks0(8) + B-ks0 nf01(2) | STAGE B1(t+1)  | BAR lgkm0 MFMA(c0,c1) BAR
//   p2: DS B-ks0 nf23(2)            | STAGE A0(t+2)  | BAR lgkm0 MFMA(c2,c3) BAR
//   p3: DS A-ks1(8) + B-ks1 nf01(2) | STAGE B0(t+2)  | BAR lgkm0 MFMA(c0,c1) BAR
//   p4: DS B-ks1 nf23(2)            | STAGE A1(t+2)  | BAR lgkm0 MFMA(c2,c3) vmcnt(6) BAR
// Each staged region was fully consumed >=1 barrier earlier; vmcnt(6) leaves
// exactly the 3 most recent regions in flight (T4 counted wait).
// T2: chunk' = chunk ^ ((row>>1)&3) swizzle applied on BOTH global source
// (pre-swizzle; LDS dest stays linear for global_load_lds) and ds_read.
// ===========================================================================
__device__ __forceinline__ void stage_region(const f16* __restrict__ src, int ldk,
                                             int row0, int rowMax, int kbase,
                                             f16* region, int t)
{
    const int lane = t & 63, wv = t >> 6;
    #pragma unroll
    for (int qq = 0; qq < 2; ++qq) {
        const int base16 = wv * 64 + qq * 512;        // wave-uniform 16B index
        const int off16  = base16 + lane;             // this lane's 16B slot
        const int row    = off16 >> 2;                // 0..255
        const int chunk  = off16 & 3;                 // 16B chunk within 64B row
        const int schunk = chunk ^ ((row >> 1) & 3);  // T2 pre-swizzled source
        int grow = row0 + row; if (grow > rowMax) grow = rowMax;
        const f16* g = src + (long long)grow * ldk + kbase + schunk * 8;
        __builtin_amdgcn_global_load_lds(GPTR(g), LPTR(region + base16 * 8), 16, 0, 0);
    }
}

#define PH_SYNC_ENTER()                                          \
    __builtin_amdgcn_sched_barrier(0);                           \
    __builtin_amdgcn_s_barrier();                                \
    asm volatile("s_waitcnt lgkmcnt(0)" ::: "memory");           \
    __builtin_amdgcn_sched_barrier(0);                           \
    __builtin_amdgcn_s_setprio(1);

#define PH_SYNC_EXIT()                                           \
    __builtin_amdgcn_s_setprio(0);                               \
    __builtin_amdgcn_sched_barrier(0);                           \
    __builtin_amdgcn_s_barrier();

__global__ __launch_bounds__(512, 2)
void gemm8p(const f16* __restrict__ A, const f16* __restrict__ B,
            float* __restrict__ C, int M, int N, int K,
            long long sA, long long sB, long long sC, int ldA, int ldB)
{
    __shared__ __align__(16) f16 SH[2][2][2][256 * 32];

    const int t    = threadIdx.x;
    const int lane = t & 63;
    const int wv   = t >> 6;
    const int wm   = wv >> 2;       // 0..1 -> 128-row half
    const int wn   = wv & 3;        // 0..3 -> 64-col strip
    const int rl   = lane & 15;
    const int swz8 = (((lane >> 4) ^ ((rl >> 1) & 3)) * 8);

    // T1: bijective XCD swizzle (m204 form; handles nwg % 8 != 0)
    const int nx = gridDim.x, nwg = nx * gridDim.y;
    {
    }
    int orig = blockIdx.y * nx + blockIdx.x;
    const int q = nwg >> 3, r = nwg & 7, xcd = orig & 7, sub = orig >> 3;
    const int wg = (xcd < r ? xcd * (q + 1) : r * (q + 1) + (xcd - r) * q) + sub;
    const int bx = wg % nx, by = wg / nx;

    const f16* Ab = A + (long long)blockIdx.z * sA;
    const f16* Bb = B + (long long)blockIdx.z * sB;
    float*     Cb = C + (long long)blockIdx.z * sC;

    const int m0 = by * 256, n0 = bx * 256;
    const int NT = K >> 6;
    const int Mm1 = M - 1, Nm1 = N - 1;

    f32x4 acc[8][4];
    #pragma unroll
    for (int i = 0; i < 8; ++i)
        #pragma unroll
        for (int j = 0; j < 4; ++j)
            acc[i][j] = (f32x4)0.f;

    // ---- prologue: tile0 all 4 regions + tile1 {A0,B0,A1}; B1(1) comes at t0.p1
    stage_region(Ab, ldA, m0, Mm1, 0,  &SH[0][0][0][0], t);
    stage_region(Bb, ldB, n0, Nm1, 0,  &SH[0][1][0][0], t);
    stage_region(Ab, ldA, m0, Mm1, 32, &SH[0][0][1][0], t);
    stage_region(Bb, ldB, n0, Nm1, 32, &SH[0][1][1][0], t);
    stage_region(Ab, ldA, m0, Mm1, 64, &SH[1][0][0][0], t);
    stage_region(Bb, ldB, n0, Nm1, 64, &SH[1][1][0][0], t);
    stage_region(Ab, ldA, m0, Mm1, 96, &SH[1][0][1][0], t);
    asm volatile("s_waitcnt vmcnt(6)" ::: "memory");   // tile0 fully landed
    __builtin_amdgcn_sched_barrier(0);
    __builtin_amdgcn_s_barrier();

    for (int tt = 0; tt < NT; ++tt) {
        const int buf = tt & 1;
        const f16* As0 = &SH[buf][0][0][0];
        const f16* As1 = &SH[buf][0][1][0];
        const f16* Bs0 = &SH[buf][1][0][0];
        const f16* Bs1 = &SH[buf][1][1][0];

        f16x8 af[8], bfa, bfb, bfc, bfd;

        // ---------------- P1 ----------------
        #pragma unroll
        for (int f = 0; f < 8; ++f)
            af[f] = *(const f16x8*)&As0[(wm * 128 + f * 16 + rl) * 32 + swz8];
        bfa = *(const f16x8*)&Bs0[(wn * 64 + 0 * 16 + rl) * 32 + swz8];
        bfb = *(const f16x8*)&Bs0[(wn * 64 + 1 * 16 + rl) * 32 + swz8];
        if (tt + 1 < NT)
            stage_region(Bb, ldB, n0, Nm1, (tt + 1) * 64 + 32, &SH[buf ^ 1][1][1][0], t);
        PH_SYNC_ENTER();
        #pragma unroll
        for (int f = 0; f < 8; ++f) {
            acc[f][0] = __builtin_amdgcn_mfma_f32_16x16x32_f16(af[f], bfa, acc[f][0], 0, 0, 0);
            acc[f][1] = __builtin_amdgcn_mfma_f32_16x16x32_f16(af[f], bfb, acc[f][1], 0, 0, 0);
        }
        PH_SYNC_EXIT();

        // ---------------- P2 ----------------
        bfc = *(const f16x8*)&Bs0[(wn * 64 + 2 * 16 + rl) * 32 + swz8];
        bfd = *(const f16x8*)&Bs0[(wn * 64 + 3 * 16 + rl) * 32 + swz8];
        if (tt + 2 < NT)
            stage_region(Ab, ldA, m0, Mm1, (tt + 2) * 64, &SH[buf][0][0][0], t);
        PH_SYNC_ENTER();
        #pragma unroll
        for (int f = 0; f < 8; ++f) {
            acc[f][2] = __builtin_amdgcn_mfma_f32_16x16x32_f16(af[f], bfc, acc[f][2], 0, 0, 0);
            acc[f][3] = __builtin_amdgcn_mfma_f32_16x16x32_f16(af[f], bfd, acc[f][3], 0, 0, 0);
        }
        PH_SYNC_EXIT();

        // ---------------- P3 ----------------
        #pragma unroll
        for (int f = 0; f < 8; ++f)
            af[f] = *(const f16x8*)&As1[(wm * 128 + f * 16 + rl) * 32 + swz8];
        bfa = *(const f16x8*)&Bs1[(wn * 64 + 0 * 16 + rl) * 32 + swz8];
        bfb = *(const f16x8*)&Bs1[(wn * 64 + 1 * 16 + rl) * 32 + swz8];
        if (tt + 2 < NT)
            stage_region(Bb, ldB, n0, Nm1, (tt + 2) * 64, &SH[buf][1][0][0], t);
        PH_SYNC_ENTER();
        #pragma unroll
        for (int f = 0; f < 8; ++f) {
            acc[f][0] = __builtin_amdgcn_mfma_f32_16x16x32_f16(af[f], bfa, acc[f][0], 0, 0, 0);
            acc[f][1] = __builtin_amdgcn_mfma_f32_16x16x32_f16(af[f], bfb, acc[f][1], 0, 0, 0);
        }
        PH_SYNC_EXIT();

        // ---------------- P4 ----------------
        bfc = *(const f16x8*)&Bs1[(wn * 64 + 2 * 16 + rl) * 32 + swz8];
        bfd = *(const f16x8*)&Bs1[(wn * 64 + 3 * 16 + rl) * 32 + swz8];
        if (tt + 2 < NT)
            stage_region(Ab, ldA, m0, Mm1, (tt + 2) * 64 + 32, &SH[buf][0][1][0], t);
        __builtin_amdgcn_sched_barrier(0);
        __builtin_amdgcn_s_barrier();
        asm volatile("s_waitcnt lgkmcnt(0)" ::: "memory");
        __builtin_amdgcn_sched_barrier(0);
        __builtin_amdgcn_s_setprio(1);
        #pragma unroll
        for (int f = 0; f < 8; ++f) {
            acc[f][2] = __builtin_amdgcn_mfma_f32_16x16x32_f16(af[f], bfc, acc[f][2], 0, 0, 0);
            acc[f][3] = __builtin_amdgcn_mfma_f32_16x16x32_f16(af[f], bfd, acc[f][3], 0, 0, 0);
        }
        __builtin_amdgcn_s_setprio(0);
        asm volatile("s_waitcnt vmcnt(6)" ::: "memory");  // T4: 3 regions stay in flight
        __builtin_amdgcn_sched_barrier(0);
        __builtin_amdgcn_s_barrier();
    }

    // ---- epilogue: scattered fp32 stores (16-lane x 64B runs) ----
    const int rq = (lane >> 4) * 4;
    #pragma unroll
    for (int f = 0; f < 8; ++f) {
        #pragma unroll
        for (int j = 0; j < 4; ++j) {
            #pragma unroll
            for (int rr = 0; rr < 4; ++rr) {
                const int row = m0 + wm * 128 + f * 16 + rq + rr;
                const int col = n0 + wn * 64 + j * 16 + rl;
                if (row < M)
                    Cb[(long long)row * N + col] = acc[f][j][rr];
            }
        }
    }
}

// ===========================================================================
// 128x128 MFMA NT GEMM from round 2 (kept for proj GEMM + fallback tiers)
// ===========================================================================
template<int S16>
__device__ inline void stage_tile(const void* srcv, int ldk, int row0, int rowMax,
                                  int kt, f16* dst, int t, int lane, int wv)
{
    if constexpr (S16) {
        const f16* src = (const f16*)srcv;
        #pragma unroll
        for (int j = 0; j < 2; ++j) {
            int r = wv * 32 + j * 16 + (lane >> 2);
            int row = row0 + r; if (row > rowMax) row = rowMax;
            const f16* g = src + (long long)row * ldk + kt + (lane & 3) * 8;
            f16* l = dst + (wv * 32 + j * 16) * 32;
            __builtin_amdgcn_global_load_lds(GPTR(g), LPTR(l), 16, 0, 0);
        }
    } else {
        const float* src = (const float*)srcv;
        int r  = t >> 1;
        int kq = (t & 1) * 16;
        int row = row0 + r; if (row > rowMax) row = rowMax;
        const float* g = src + (long long)row * ldk + kt + kq;
        float4 v0 = ((const float4*)g)[0];
        float4 v1 = ((const float4*)g)[1];
        float4 v2 = ((const float4*)g)[2];
        float4 v3 = ((const float4*)g)[3];
        f16x8 h0, h1;
        h0[0]=(f16)v0.x; h0[1]=(f16)v0.y; h0[2]=(f16)v0.z; h0[3]=(f16)v0.w;
        h0[4]=(f16)v1.x; h0[5]=(f16)v1.y; h0[6]=(f16)v1.z; h0[7]=(f16)v1.w;
        h1[0]=(f16)v2.x; h1[1]=(f16)v2.y; h1[2]=(f16)v2.z; h1[3]=(f16)v2.w;
        h1[4]=(f16)v3.x; h1[5]=(f16)v3.y; h1[6]=(f16)v3.z; h1[7]=(f16)v3.w;
        *(f16x8*)&dst[r * 32 + kq]     = h0;
        *(f16x8*)&dst[r * 32 + kq + 8] = h1;
    }
}

template<int SA, int SB, int OUTMODE>
__global__ __launch_bounds__(256)
void mfma_nt(const void* __restrict__ A, const void* __restrict__ B,
             void* __restrict__ C, int M, int N, int K,
             long long sA, long long sB, long long sC, int ldA, int ldB)
{
    const char* Ab = (const char*)A + (long long)blockIdx.z * sA * (SA ? 2 : 4);
    const char* Bb = (const char*)B + (long long)blockIdx.z * sB * (SB ? 2 : 4);

    __shared__ __align__(16) f16 As[128 * 32];
    __shared__ __align__(16) f16 Bs[128 * 32];

    const int t    = threadIdx.x;
    const int lane = t & 63;
    const int wv   = t >> 6;
    const int wr   = wv >> 1;
    const int wc   = wv & 1;
    const int m0   = blockIdx.y * 128;
    const int n0   = blockIdx.x * 128;

    f32x4 acc[4][4] = {};

    for (int kt = 0; kt < K; kt += 32) {
        stage_tile<SA>(Ab, ldA, m0, M - 1, kt, As, t, lane, wv);
        stage_tile<SB>(Bb, ldB, n0, N - 1, kt, Bs, t, lane, wv);
        __syncthreads();

        f16x8 af[4], bf[4];
        const int kc = (lane >> 4) * 8;
        const int rl = lane & 15;
        #pragma unroll
        for (int i = 0; i < 4; ++i)
            af[i] = *(const f16x8*)&As[(wr * 64 + i * 16 + rl) * 32 + kc];
        #pragma unroll
        for (int j = 0; j < 4; ++j)
            bf[j] = *(const f16x8*)&Bs[(wc * 64 + j * 16 + rl) * 32 + kc];

        #pragma unroll
        for (int i = 0; i < 4; ++i)
            #pragma unroll
            for (int j = 0; j < 4; ++j)
                acc[i][j] = __builtin_amdgcn_mfma_f32_16x16x32_f16(af[i], bf[j], acc[i][j], 0, 0, 0);
        __syncthreads();
    }

    const int rquad = (lane >> 4) * 4;
    const int rcol  = lane & 15;
    #pragma unroll
    for (int i = 0; i < 4; ++i) {
        #pragma unroll
        for (int j = 0; j < 4; ++j) {
            #pragma unroll
            for (int r = 0; r < 4; ++r) {
                int row = m0 + wr * 64 + i * 16 + rquad + r;
                int col = n0 + wc * 64 + j * 16 + rcol;
                if (row < M) {
                    if constexpr (OUTMODE == 1)
                        ((f16*)C)[(long long)row * N + col] = (f16)tanhf(acc[i][j][r]);
                    else
                        ((float*)C + (long long)blockIdx.z * sC)[(long long)row * N + col] = acc[i][j][r];
                }
            }
        }
    }
}

// ===========================================================================
__global__ __launch_bounds__(256)
void cvt_f32_f16(const float* __restrict__ in, f16* __restrict__ out, long long n4)
{
    long long i = (long long)blockIdx.x * 256 + threadIdx.x;
    if (i < n4) {
        float4 v = ((const float4*)in)[i];
        f16 h[4] = {(f16)v.x, (f16)v.y, (f16)v.z, (f16)v.w};
        *(uint2*)&out[i * 4] = *(uint2*)h;
    }
}

__global__ __launch_bounds__(256)
void transpose_f16(const float* __restrict__ in, f16* __restrict__ out)
{
    __shared__ float tile[32][33];
    const int b  = blockIdx.z;
    const int h0 = blockIdx.x * 32, s0 = blockIdx.y * 32;
    in  += (long long)b * SEQN * HD;
    out += (long long)b * HD * SEQN;
    const int tx = threadIdx.x & 31, ty = threadIdx.x >> 5;
    #pragma unroll
    for (int i = ty; i < 32; i += 8)
        tile[i][tx] = in[(long long)(s0 + i) * HD + h0 + tx];
    __syncthreads();
    #pragma unroll
    for (int i = ty; i < 32; i += 8)
        out[(long long)(h0 + i) * SEQN + s0 + tx] = (f16)tile[tx][i];
}

template<bool W16>
__global__ __launch_bounds__(256)
void softmax_rows(float* __restrict__ data, f16* __restrict__ data16)
{
    const long long row = blockIdx.x;
    float* p = data + row * (long long)SEQN;
    const int t = threadIdx.x;

    float4 v[4];
    float vmax = -INFINITY;
    #pragma unroll
    for (int i = 0; i < 4; ++i) {
        v[i] = ((const float4*)p)[t + 256 * i];
        vmax = fmaxf(vmax, fmaxf(fmaxf(v[i].x, v[i].y), fmaxf(v[i].z, v[i].w)));
    }
    #pragma unroll
    for (int off = 32; off > 0; off >>= 1)
        vmax = fmaxf(vmax, __shfl_xor(vmax, off));

    __shared__ float redmax[4];
    __shared__ float redsum[4];
    if ((t & 63) == 0) redmax[t >> 6] = vmax;
    __syncthreads();
    vmax = fmaxf(fmaxf(redmax[0], redmax[1]), fmaxf(redmax[2], redmax[3]));

    float sum = 0.f;
    #pragma unroll
    for (int i = 0; i < 4; ++i) {
        v[i].x = expf(v[i].x - vmax);
        v[i].y = expf(v[i].y - vmax);
        v[i].z = expf(v[i].z - vmax);
        v[i].w = expf(v[i].w - vmax);
        sum += (v[i].x + v[i].y) + (v[i].z + v[i].w);
    }
    #pragma unroll
    for (int off = 32; off > 0; off >>= 1)
        sum += __shfl_xor(sum, off);
    if ((t & 63) == 0) redsum[t >> 6] = sum;
    __syncthreads();
    sum = (redsum[0] + redsum[1]) + (redsum[2] + redsum[3]);

    const float inv = 1.0f / sum;
    #pragma unroll
    for (int i = 0; i < 4; ++i) {
        v[i].x *= inv; v[i].y *= inv; v[i].z *= inv; v[i].w *= inv;
        ((float4*)p)[t + 256 * i] = v[i];
        if constexpr (W16) {
            f16 h[4] = {(f16)v[i].x, (f16)v[i].y, (f16)v[i].z, (f16)v[i].w};
            *(uint2*)&data16[row * (long long)SEQN + (t + 256 * i) * 4] = *(uint2*)h;
        }
    }
}

// ===========================================================================
// Tier-C fp32 fallback (round 1 pipeline)
// ===========================================================================
#define BMF 64
#define BNF 64
#define BKF 16
#define PADF 4

template<bool TANH>
__global__ __launch_bounds__(256)
void nt_gemm(const float* __restrict__ A, const float* __restrict__ B,
             float* __restrict__ C, int M, int N, int K,
             long long sA, long long sB, long long sC)
{
    A += (long long)blockIdx.z * sA;
    B += (long long)blockIdx.z * sB;
    C += (long long)blockIdx.z * sC;
    __shared__ __align__(16) float As[BKF][BMF + PADF];
    __shared__ __align__(16) float Bs[BKF][BNF + PADF];
    const int t = threadIdx.x;
    const int m0 = blockIdx.y * BMF, n0 = blockIdx.x * BNF;
    const int tx = t & 15, ty = t >> 4, lr = t >> 2, lk = (t & 3) * 4;
    float acc[4][4] = {};
    for (int kt = 0; kt < K; kt += BKF) {
        {
            float4 v = make_float4(0.f, 0.f, 0.f, 0.f);
            int m = m0 + lr;
            if (m < M) v = *(const float4*)(A + (long long)m * K + kt + lk);
            As[lk+0][lr]=v.x; As[lk+1][lr]=v.y; As[lk+2][lr]=v.z; As[lk+3][lr]=v.w;
        }
        {
            float4 v = make_float4(0.f, 0.f, 0.f, 0.f);
            int n = n0 + lr;
            if (n < N) v = *(const float4*)(B + (long long)n * K + kt + lk);
            Bs[lk+0][lr]=v.x; Bs[lk+1][lr]=v.y; Bs[lk+2][lr]=v.z; Bs[lk+3][lr]=v.w;
        }
        __syncthreads();
        #pragma unroll
        for (int k = 0; k < BKF; ++k) {
            float4 a = *(const float4*)(&As[k][ty * 4]);
            float4 b = *(const float4*)(&Bs[k][tx * 4]);
            float av[4]={a.x,a.y,a.z,a.w}, bv[4]={b.x,b.y,b.z,b.w};
            #pragma unroll
            for (int i = 0; i < 4; ++i)
                #pragma unroll
                for (int j = 0; j < 4; ++j)
                    acc[i][j] = fmaf(av[i], bv[j], acc[i][j]);
        }
        __syncthreads();
    }
    #pragma unroll
    for (int i = 0; i < 4; ++i) {
        int m = m0 + ty * 4 + i;
        if (m < M) {
            float4 r;
            r.x = TANH ? tanhf(acc[i][0]) : acc[i][0];
            r.y = TANH ? tanhf(acc[i][1]) : acc[i][1];
            r.z = TANH ? tanhf(acc[i][2]) : acc[i][2];
            r.w = TANH ? tanhf(acc[i][3]) : acc[i][3];
            *(float4*)(C + (long long)m * N + n0 + tx * 4) = r;
        }
    }
}

__global__ __launch_bounds__(256)
void nn_gemm(const float* __restrict__ A, const float* __restrict__ B,
             float* __restrict__ C, int M, int N, int K,
             long long sA, long long sB, long long sC)
{
    A += (long long)blockIdx.z * sA;
    B += (long long)blockIdx.z * sB;
    C += (long long)blockIdx.z * sC;
    __shared__ __align__(16) float As[BKF][BMF + PADF];
    __shared__ __align__(16) float Bs[BKF][BNF + PADF];
    const int t = threadIdx.x;
    const int m0 = blockIdx.y * BMF, n0 = blockIdx.x * BNF;
    const int tx = t & 15, ty = t >> 4, lr = t >> 2, lk = (t & 3) * 4;
    const int kr = t >> 4, cq = (t & 15) * 4;
    float acc[4][4] = {};
    for (int kt = 0; kt < K; kt += BKF) {
        {
            float4 v = make_float4(0.f, 0.f, 0.f, 0.f);
            int m = m0 + lr;
            if (m < M) v = *(const float4*)(A + (long long)m * K + kt + lk);
            As[lk+0][lr]=v.x; As[lk+1][lr]=v.y; As[lk+2][lr]=v.z; As[lk+3][lr]=v.w;
        }
        {
            float4 v = *(const float4*)(B + (long long)(kt + kr) * N + n0 + cq);
            *(float4*)(&Bs[kr][cq]) = v;
        }
        __syncthreads();
        #pragma unroll
        for (int k = 0; k < BKF; ++k) {
            float4 a = *(const float4*)(&As[k][ty * 4]);
            float4 b = *(const float4*)(&Bs[k][tx * 4]);
            float av[4]={a.x,a.y,a.z,a.w}, bv[4]={b.x,b.y,b.z,b.w};
            #pragma unroll
            for (int i = 0; i < 4; ++i)
                #pragma unroll
                for (int j = 0; j < 4; ++j)
                    acc[i][j] = fmaf(av[i], bv[j], acc[i][j]);
        }
        __syncthreads();
    }
    #pragma unroll
    for (int i = 0; i < 4; ++i) {
        int m = m0 + ty * 4 + i;
        if (m < M)
            *(float4*)(C + (long long)m * N + n0 + tx * 4) =
                make_float4(acc[i][0], acc[i][1], acc[i][2], acc[i][3]);
    }
}

// ===========================================================================
extern "C" void kernel_launch(void* const* d_in, const int* in_sizes, int n_in,
                              void* d_out, int out_size, void* d_ws, size_t ws_size,
                              hipStream_t stream)
{
    const float* code = (const float*)d_in[0];   // (L, H)
    const float* text = (const float*)d_in[1];   // (BS, SEQ, H)
    const float* Wm   = (const float*)d_in[3];   // (H, H)

    float* att  = (float*)d_out;                          // (BS, L, SEQ)
    float* wout = att + (long long)BSZ * NL * SEQN;       // (BS, L, H)

    const long long n_code  = (long long)NL * HD;
    const long long n_proj  = (long long)BSZ * SEQN * HD;
    const long long n_textT = (long long)BSZ * HD * SEQN;
    const long long n_att   = (long long)BSZ * NL * SEQN;
    const size_t base_bytes = (size_t)(n_code + n_proj + n_textT) * 2;
    const size_t full_bytes = base_bytes + (size_t)n_att * 2;

    if (ws_size < base_bytes) {
        // ---- Tier C: fp32 fallback ----
        float* proj = wout;
        dim3 g1(HD / BNF, (BSZ * SEQN) / BMF, 1);
        hipLaunchKernelGGL((nt_gemm<true>), g1, dim3(256), 0, stream,
                           text, Wm, proj, BSZ * SEQN, HD, HD, 0LL, 0LL, 0LL);
        dim3 g2(SEQN / BNF, (NL + BMF - 1) / BMF, BSZ);
        hipLaunchKernelGGL((nt_gemm<false>), g2, dim3(256), 0, stream,
                           code, proj, att, NL, SEQN, HD,
                           0LL, (long long)SEQN * HD, (long long)NL * SEQN);
        hipLaunchKernelGGL((softmax_rows<false>), dim3(BSZ * NL), dim3(256), 0, stream, att, (f16*)nullptr);
        dim3 g4(HD / BNF, (NL + BMF - 1) / BMF, BSZ);
        hipLaunchKernelGGL(nn_gemm, g4, dim3(256), 0, stream,
                           att, text, wout, NL, HD, SEQN,
                           (long long)NL * SEQN, (long long)SEQN * HD, (long long)NL * HD);
        return;
    }

    f16* code_h  = (f16*)d_ws;
    f16* proj_h  = code_h + n_code;
    f16* textT_h = proj_h + n_proj;
    f16* att_h   = textT_h + n_textT;
    const bool has_att16 = ws_size >= full_bytes;

    // 0a) code -> f16
    {
        long long n4 = n_code / 4;
        hipLaunchKernelGGL(cvt_f32_f16, dim3((unsigned)((n4 + 255) / 256)), dim3(256), 0, stream,
                           code, code_h, n4);
    }
    // 0b) text -> textT f16 (BS, HD, SEQN)
    {
        dim3 g(HD / 32, SEQN / 32, BSZ);
        hipLaunchKernelGGL(transpose_f16, g, dim3(256), 0, stream, text, textT_h);
    }
    // 1) proj_h = tanh(text @ W^T) as f16
    {
        dim3 g(HD / 128, (BSZ * SEQN) / 128, 1);
        hipLaunchKernelGGL((mfma_nt<0, 0, 1>), g, dim3(256), 0, stream,
                           text, Wm, proj_h, BSZ * SEQN, HD, HD, 0LL, 0LL, 0LL, HD, HD);
    }
    // 2) att_b = code @ proj_b^T : M=8921, N=4096, K=768 (NT=12)
    {
        dim3 g(SEQN / 256, (NL + 255) / 256, BSZ);
        hipLaunchKernelGGL(gemm8p, g, dim3(512), 0, stream,
                           code_h, proj_h, att, NL, SEQN, HD,
                           0LL, (long long)SEQN * HD, (long long)NL * SEQN, HD, HD);
    }
    // 3) softmax over seq (in place) + f16 copy
    if (has_att16)
        hipLaunchKernelGGL((softmax_rows<true>), dim3(BSZ * NL), dim3(256), 0, stream, att, att_h);
    else
        hipLaunchKernelGGL((softmax_rows<false>), dim3(BSZ * NL), dim3(256), 0, stream, att, (f16*)nullptr);
    // 4) wout_b = att_b @ textT_b^T : M=8921, N=768, K=4096 (NT=64)
    if (has_att16) {
        dim3 g(HD / 256, (NL + 255) / 256, BSZ);
        hipLaunchKernelGGL(gemm8p, g, dim3(512), 0, stream,
                           att_h, textT_h, wout, NL, HD, SEQN,
                           (long long)NL * SEQN, (long long)HD * SEQN, (long long)NL * HD,
                           SEQN, SEQN);
    } else {
        dim3 g(HD / 128, (NL + 127) / 128, BSZ);
        hipLaunchKernelGGL((mfma_nt<0, 1, 0>), g, dim3(256), 0, stream,
                           att, textT_h, wout, NL, HD, SEQN,
                           (long long)NL * SEQN, (long long)HD * SEQN, (long long)NL * HD,
                           SEQN, SEQN);
    }
}

// Round 4
// 418.828 us; speedup vs baseline: 7.5409x; 1.1503x over previous
//
#include <hip/hip_runtime.h>
#include <math.h>

#define BSZ  2
#define SEQN 4096
#define HD   768
#define NL   8921

typedef _Float16 f16;
typedef f16   f16x8 __attribute__((ext_vector_type(8)));
typedef float f32x4 __attribute__((ext_vector_type(4)));

#define GPTR(p) ((const __attribute__((address_space(1))) void*)(p))
#define LPTR(p) ((__attribute__((address_space(3))) void*)(p))

// ===========================================================================
// 8-phase 256x256 NT GEMM (f16 in, fp32/f16 out), BK=64, 8 waves (2Mx4N),
// mfma_f32_16x16x32_f16. LDS [2 dbuf][A/B][2 ksub][256 rows][32 k] = 128 KiB.
// Region ledger per K-tile (4 phases), each staged region fully consumed
// >= 1 barrier earlier; vmcnt(6) keeps exactly 3 regions in flight (T4).
// T2 chunk-XOR swizzle on BOTH global source and ds_read (m231 rule).
// OUT: 0 = fp32 C, 1 = f16 C.
// ===========================================================================
__device__ __forceinline__ void stage_region(const f16* __restrict__ src, int ldk,
                                             int row0, int rowMax, int kbase,
                                             f16* region, int t)
{
    const int lane = t & 63, wv = t >> 6;
    #pragma unroll
    for (int qq = 0; qq < 2; ++qq) {
        const int base16 = wv * 64 + qq * 512;        // wave-uniform 16B index
        const int off16  = base16 + lane;             // this lane's 16B slot
        const int row    = off16 >> 2;                // 0..255
        const int chunk  = off16 & 3;                 // 16B chunk within 64B row
        const int schunk = chunk ^ ((row >> 1) & 3);  // T2 pre-swizzled source
        int grow = row0 + row; if (grow > rowMax) grow = rowMax;
        const f16* g = src + (long long)grow * ldk + kbase + schunk * 8;
        __builtin_amdgcn_global_load_lds(GPTR(g), LPTR(region + base16 * 8), 16, 0, 0);
    }
}

#define PH_SYNC_ENTER()                                          \
    __builtin_amdgcn_sched_barrier(0);                           \
    __builtin_amdgcn_s_barrier();                                \
    asm volatile("s_waitcnt lgkmcnt(0)" ::: "memory");           \
    __builtin_amdgcn_sched_barrier(0);                           \
    __builtin_amdgcn_s_setprio(1);

#define PH_SYNC_EXIT()                                           \
    __builtin_amdgcn_s_setprio(0);                               \
    __builtin_amdgcn_sched_barrier(0);                           \
    __builtin_amdgcn_s_barrier();

template<int OUT>
__global__ __launch_bounds__(512, 2)
void gemm8p(const f16* __restrict__ A, const f16* __restrict__ B,
            void* __restrict__ C, int M, int N, int K,
            long long sA, long long sB, long long sC, int ldA, int ldB)
{
    __shared__ __align__(16) f16 SH[2][2][2][256 * 32];

    const int t    = threadIdx.x;
    const int lane = t & 63;
    const int wv   = t >> 6;
    const int wm   = wv >> 2;       // 0..1 -> 128-row half
    const int wn   = wv & 3;        // 0..3 -> 64-col strip
    const int rl   = lane & 15;
    const int swz8 = (((lane >> 4) ^ ((rl >> 1) & 3)) * 8);

    // T1: bijective XCD swizzle (m204 form)
    const int nx = gridDim.x, nwg = nx * gridDim.y;
    int orig = blockIdx.y * nx + blockIdx.x;
    const int q = nwg >> 3, r = nwg & 7, xcd = orig & 7, sub = orig >> 3;
    const int wg = (xcd < r ? xcd * (q + 1) : r * (q + 1) + (xcd - r) * q) + sub;
    const int bx = wg % nx, by = wg / nx;

    const f16* Ab = A + (long long)blockIdx.z * sA;
    const f16* Bb = B + (long long)blockIdx.z * sB;

    const int m0 = by * 256, n0 = bx * 256;
    const int NT = K >> 6;
    const int Mm1 = M - 1, Nm1 = N - 1;

    f32x4 acc[8][4];
    #pragma unroll
    for (int i = 0; i < 8; ++i)
        #pragma unroll
        for (int j = 0; j < 4; ++j)
            acc[i][j] = (f32x4)0.f;

    // ---- prologue: tile0 all 4 regions + tile1 {A0,B0,A1}; B1(1) comes at t0.p1
    stage_region(Ab, ldA, m0, Mm1, 0,  &SH[0][0][0][0], t);
    stage_region(Bb, ldB, n0, Nm1, 0,  &SH[0][1][0][0], t);
    stage_region(Ab, ldA, m0, Mm1, 32, &SH[0][0][1][0], t);
    stage_region(Bb, ldB, n0, Nm1, 32, &SH[0][1][1][0], t);
    stage_region(Ab, ldA, m0, Mm1, 64, &SH[1][0][0][0], t);
    stage_region(Bb, ldB, n0, Nm1, 64, &SH[1][1][0][0], t);
    stage_region(Ab, ldA, m0, Mm1, 96, &SH[1][0][1][0], t);
    asm volatile("s_waitcnt vmcnt(6)" ::: "memory");   // tile0 fully landed
    __builtin_amdgcn_sched_barrier(0);
    __builtin_amdgcn_s_barrier();

    for (int tt = 0; tt < NT; ++tt) {
        const int buf = tt & 1;
        const f16* As0 = &SH[buf][0][0][0];
        const f16* As1 = &SH[buf][0][1][0];
        const f16* Bs0 = &SH[buf][1][0][0];
        const f16* Bs1 = &SH[buf][1][1][0];

        f16x8 af[8], bfa, bfb, bfc, bfd;

        // ---------------- P1 ----------------
        #pragma unroll
        for (int f = 0; f < 8; ++f)
            af[f] = *(const f16x8*)&As0[(wm * 128 + f * 16 + rl) * 32 + swz8];
        bfa = *(const f16x8*)&Bs0[(wn * 64 + 0 * 16 + rl) * 32 + swz8];
        bfb = *(const f16x8*)&Bs0[(wn * 64 + 1 * 16 + rl) * 32 + swz8];
        if (tt + 1 < NT)
            stage_region(Bb, ldB, n0, Nm1, (tt + 1) * 64 + 32, &SH[buf ^ 1][1][1][0], t);
        PH_SYNC_ENTER();
        #pragma unroll
        for (int f = 0; f < 8; ++f) {
            acc[f][0] = __builtin_amdgcn_mfma_f32_16x16x32_f16(af[f], bfa, acc[f][0], 0, 0, 0);
            acc[f][1] = __builtin_amdgcn_mfma_f32_16x16x32_f16(af[f], bfb, acc[f][1], 0, 0, 0);
        }
        PH_SYNC_EXIT();

        // ---------------- P2 ----------------
        bfc = *(const f16x8*)&Bs0[(wn * 64 + 2 * 16 + rl) * 32 + swz8];
        bfd = *(const f16x8*)&Bs0[(wn * 64 + 3 * 16 + rl) * 32 + swz8];
        if (tt + 2 < NT)
            stage_region(Ab, ldA, m0, Mm1, (tt + 2) * 64, &SH[buf][0][0][0], t);
        PH_SYNC_ENTER();
        #pragma unroll
        for (int f = 0; f < 8; ++f) {
            acc[f][2] = __builtin_amdgcn_mfma_f32_16x16x32_f16(af[f], bfc, acc[f][2], 0, 0, 0);
            acc[f][3] = __builtin_amdgcn_mfma_f32_16x16x32_f16(af[f], bfd, acc[f][3], 0, 0, 0);
        }
        PH_SYNC_EXIT();

        // ---------------- P3 ----------------
        #pragma unroll
        for (int f = 0; f < 8; ++f)
            af[f] = *(const f16x8*)&As1[(wm * 128 + f * 16 + rl) * 32 + swz8];
        bfa = *(const f16x8*)&Bs1[(wn * 64 + 0 * 16 + rl) * 32 + swz8];
        bfb = *(const f16x8*)&Bs1[(wn * 64 + 1 * 16 + rl) * 32 + swz8];
        if (tt + 2 < NT)
            stage_region(Bb, ldB, n0, Nm1, (tt + 2) * 64, &SH[buf][1][0][0], t);
        PH_SYNC_ENTER();
        #pragma unroll
        for (int f = 0; f < 8; ++f) {
            acc[f][0] = __builtin_amdgcn_mfma_f32_16x16x32_f16(af[f], bfa, acc[f][0], 0, 0, 0);
            acc[f][1] = __builtin_amdgcn_mfma_f32_16x16x32_f16(af[f], bfb, acc[f][1], 0, 0, 0);
        }
        PH_SYNC_EXIT();

        // ---------------- P4 ----------------
        bfc = *(const f16x8*)&Bs1[(wn * 64 + 2 * 16 + rl) * 32 + swz8];
        bfd = *(const f16x8*)&Bs1[(wn * 64 + 3 * 16 + rl) * 32 + swz8];
        if (tt + 2 < NT)
            stage_region(Ab, ldA, m0, Mm1, (tt + 2) * 64 + 32, &SH[buf][0][1][0], t);
        __builtin_amdgcn_sched_barrier(0);
        __builtin_amdgcn_s_barrier();
        asm volatile("s_waitcnt lgkmcnt(0)" ::: "memory");
        __builtin_amdgcn_sched_barrier(0);
        __builtin_amdgcn_s_setprio(1);
        #pragma unroll
        for (int f = 0; f < 8; ++f) {
            acc[f][2] = __builtin_amdgcn_mfma_f32_16x16x32_f16(af[f], bfc, acc[f][2], 0, 0, 0);
            acc[f][3] = __builtin_amdgcn_mfma_f32_16x16x32_f16(af[f], bfd, acc[f][3], 0, 0, 0);
        }
        __builtin_amdgcn_s_setprio(0);
        asm volatile("s_waitcnt vmcnt(6)" ::: "memory");  // T4: 3 regions in flight
        __builtin_amdgcn_sched_barrier(0);
        __builtin_amdgcn_s_barrier();
    }

    // ---- epilogue ----
    const int rq = (lane >> 4) * 4;
    #pragma unroll
    for (int f = 0; f < 8; ++f) {
        #pragma unroll
        for (int j = 0; j < 4; ++j) {
            #pragma unroll
            for (int rr = 0; rr < 4; ++rr) {
                const int row = m0 + wm * 128 + f * 16 + rq + rr;
                const int col = n0 + wn * 64 + j * 16 + rl;
                if (row < M) {
                    if constexpr (OUT == 1)
                        ((f16*)C + (long long)blockIdx.z * sC)[(long long)row * N + col] = (f16)acc[f][j][rr];
                    else
                        ((float*)C + (long long)blockIdx.z * sC)[(long long)row * N + col] = acc[f][j][rr];
                }
            }
        }
    }
}

// ===========================================================================
// 128x128 MFMA NT GEMM (proj GEMM: fp32 sources, tanh->f16 out)
// ===========================================================================
template<int S16>
__device__ inline void stage_tile(const void* srcv, int ldk, int row0, int rowMax,
                                  int kt, f16* dst, int t, int lane, int wv)
{
    if constexpr (S16) {
        const f16* src = (const f16*)srcv;
        #pragma unroll
        for (int j = 0; j < 2; ++j) {
            int r = wv * 32 + j * 16 + (lane >> 2);
            int row = row0 + r; if (row > rowMax) row = rowMax;
            const f16* g = src + (long long)row * ldk + kt + (lane & 3) * 8;
            f16* l = dst + (wv * 32 + j * 16) * 32;
            __builtin_amdgcn_global_load_lds(GPTR(g), LPTR(l), 16, 0, 0);
        }
    } else {
        const float* src = (const float*)srcv;
        int r  = t >> 1;
        int kq = (t & 1) * 16;
        int row = row0 + r; if (row > rowMax) row = rowMax;
        const float* g = src + (long long)row * ldk + kt + kq;
        float4 v0 = ((const float4*)g)[0];
        float4 v1 = ((const float4*)g)[1];
        float4 v2 = ((const float4*)g)[2];
        float4 v3 = ((const float4*)g)[3];
        f16x8 h0, h1;
        h0[0]=(f16)v0.x; h0[1]=(f16)v0.y; h0[2]=(f16)v0.z; h0[3]=(f16)v0.w;
        h0[4]=(f16)v1.x; h0[5]=(f16)v1.y; h0[6]=(f16)v1.z; h0[7]=(f16)v1.w;
        h1[0]=(f16)v2.x; h1[1]=(f16)v2.y; h1[2]=(f16)v2.z; h1[3]=(f16)v2.w;
        h1[4]=(f16)v3.x; h1[5]=(f16)v3.y; h1[6]=(f16)v3.z; h1[7]=(f16)v3.w;
        *(f16x8*)&dst[r * 32 + kq]     = h0;
        *(f16x8*)&dst[r * 32 + kq + 8] = h1;
    }
}

template<int SA, int SB, int OUTMODE>
__global__ __launch_bounds__(256)
void mfma_nt(const void* __restrict__ A, const void* __restrict__ B,
             void* __restrict__ C, int M, int N, int K,
             long long sA, long long sB, long long sC, int ldA, int ldB)
{
    const char* Ab = (const char*)A + (long long)blockIdx.z * sA * (SA ? 2 : 4);
    const char* Bb = (const char*)B + (long long)blockIdx.z * sB * (SB ? 2 : 4);

    __shared__ __align__(16) f16 As[128 * 32];
    __shared__ __align__(16) f16 Bs[128 * 32];

    const int t    = threadIdx.x;
    const int lane = t & 63;
    const int wv   = t >> 6;
    const int wr   = wv >> 1;
    const int wc   = wv & 1;
    const int m0   = blockIdx.y * 128;
    const int n0   = blockIdx.x * 128;

    f32x4 acc[4][4] = {};

    for (int kt = 0; kt < K; kt += 32) {
        stage_tile<SA>(Ab, ldA, m0, M - 1, kt, As, t, lane, wv);
        stage_tile<SB>(Bb, ldB, n0, N - 1, kt, Bs, t, lane, wv);
        __syncthreads();

        f16x8 af[4], bf[4];
        const int kc = (lane >> 4) * 8;
        const int rl = lane & 15;
        #pragma unroll
        for (int i = 0; i < 4; ++i)
            af[i] = *(const f16x8*)&As[(wr * 64 + i * 16 + rl) * 32 + kc];
        #pragma unroll
        for (int j = 0; j < 4; ++j)
            bf[j] = *(const f16x8*)&Bs[(wc * 64 + j * 16 + rl) * 32 + kc];

        #pragma unroll
        for (int i = 0; i < 4; ++i)
            #pragma unroll
            for (int j = 0; j < 4; ++j)
                acc[i][j] = __builtin_amdgcn_mfma_f32_16x16x32_f16(af[i], bf[j], acc[i][j], 0, 0, 0);
        __syncthreads();
    }

    const int rquad = (lane >> 4) * 4;
    const int rcol  = lane & 15;
    #pragma unroll
    for (int i = 0; i < 4; ++i) {
        #pragma unroll
        for (int j = 0; j < 4; ++j) {
            #pragma unroll
            for (int r = 0; r < 4; ++r) {
                int row = m0 + wr * 64 + i * 16 + rquad + r;
                int col = n0 + wc * 64 + j * 16 + rcol;
                if (row < M) {
                    if constexpr (OUTMODE == 1)
                        ((f16*)C)[(long long)row * N + col] = (f16)tanhf(acc[i][j][r]);
                    else
                        ((float*)C + (long long)blockIdx.z * sC)[(long long)row * N + col] = acc[i][j][r];
                }
            }
        }
    }
}

// ===========================================================================
__global__ __launch_bounds__(256)
void cvt_f32_f16(const float* __restrict__ in, f16* __restrict__ out, long long n4)
{
    long long i = (long long)blockIdx.x * 256 + threadIdx.x;
    if (i < n4) {
        float4 v = ((const float4*)in)[i];
        f16 h[4] = {(f16)v.x, (f16)v.y, (f16)v.z, (f16)v.w};
        *(uint2*)&out[i * 4] = *(uint2*)h;
    }
}

__global__ __launch_bounds__(256)
void transpose_f16(const float* __restrict__ in, f16* __restrict__ out)
{
    __shared__ float tile[32][33];
    const int b  = blockIdx.z;
    const int h0 = blockIdx.x * 32, s0 = blockIdx.y * 32;
    in  += (long long)b * SEQN * HD;
    out += (long long)b * HD * SEQN;
    const int tx = threadIdx.x & 31, ty = threadIdx.x >> 5;
    #pragma unroll
    for (int i = ty; i < 32; i += 8)
        tile[i][tx] = in[(long long)(s0 + i) * HD + h0 + tx];
    __syncthreads();
    #pragma unroll
    for (int i = ty; i < 32; i += 8)
        out[(long long)(h0 + i) * SEQN + s0 + tx] = (f16)tile[tx][i];
}

// ===========================================================================
// Row softmax: reads f16 scores (ws), writes fp32 att (d_out) + normalized
// f16 IN PLACE over the scores buffer (consumed by step-4 as A).
// One block (256 thr) per row of 4096.
// ===========================================================================
__global__ __launch_bounds__(256)
void softmax_f16(f16* __restrict__ scores, float* __restrict__ att)
{
    const long long row = blockIdx.x;
    f16*   ps = scores + row * (long long)SEQN;
    float* pa = att    + row * (long long)SEQN;
    const int t = threadIdx.x;

    f16x8 h[2];
    float x[2][8];
    float vmax = -INFINITY;
    #pragma unroll
    for (int i = 0; i < 2; ++i) {
        h[i] = ((const f16x8*)ps)[t + 256 * i];
        #pragma unroll
        for (int j = 0; j < 8; ++j) {
            x[i][j] = (float)h[i][j];
            vmax = fmaxf(vmax, x[i][j]);
        }
    }
    #pragma unroll
    for (int off = 32; off > 0; off >>= 1)
        vmax = fmaxf(vmax, __shfl_xor(vmax, off));

    __shared__ float redmax[4];
    __shared__ float redsum[4];
    if ((t & 63) == 0) redmax[t >> 6] = vmax;
    __syncthreads();
    vmax = fmaxf(fmaxf(redmax[0], redmax[1]), fmaxf(redmax[2], redmax[3]));

    float sum = 0.f;
    #pragma unroll
    for (int i = 0; i < 2; ++i)
        #pragma unroll
        for (int j = 0; j < 8; ++j) {
            x[i][j] = expf(x[i][j] - vmax);
            sum += x[i][j];
        }
    #pragma unroll
    for (int off = 32; off > 0; off >>= 1)
        sum += __shfl_xor(sum, off);
    if ((t & 63) == 0) redsum[t >> 6] = sum;
    __syncthreads();
    sum = (redsum[0] + redsum[1]) + (redsum[2] + redsum[3]);

    const float inv = 1.0f / sum;
    #pragma unroll
    for (int i = 0; i < 2; ++i) {
        f16x8 hn;
        #pragma unroll
        for (int j = 0; j < 8; ++j) {
            x[i][j] *= inv;
            hn[j] = (f16)x[i][j];
        }
        float4 lo = make_float4(x[i][0], x[i][1], x[i][2], x[i][3]);
        float4 hi = make_float4(x[i][4], x[i][5], x[i][6], x[i][7]);
        ((float4*)pa)[(t + 256 * i) * 2 + 0] = lo;
        ((float4*)pa)[(t + 256 * i) * 2 + 1] = hi;
        ((f16x8*)ps)[t + 256 * i] = hn;
    }
}

// ===========================================================================
// Tier-C fp32 fallback (round 1 pipeline, fp32 softmax variant included)
// ===========================================================================
#define BMF 64
#define BNF 64
#define BKF 16
#define PADF 4

__global__ __launch_bounds__(256)
void softmax_rows_f32(float* __restrict__ data)
{
    const long long row = blockIdx.x;
    float* p = data + row * (long long)SEQN;
    const int t = threadIdx.x;
    float4 v[4];
    float vmax = -INFINITY;
    #pragma unroll
    for (int i = 0; i < 4; ++i) {
        v[i] = ((const float4*)p)[t + 256 * i];
        vmax = fmaxf(vmax, fmaxf(fmaxf(v[i].x, v[i].y), fmaxf(v[i].z, v[i].w)));
    }
    #pragma unroll
    for (int off = 32; off > 0; off >>= 1)
        vmax = fmaxf(vmax, __shfl_xor(vmax, off));
    __shared__ float redmax[4];
    __shared__ float redsum[4];
    if ((t & 63) == 0) redmax[t >> 6] = vmax;
    __syncthreads();
    vmax = fmaxf(fmaxf(redmax[0], redmax[1]), fmaxf(redmax[2], redmax[3]));
    float sum = 0.f;
    #pragma unroll
    for (int i = 0; i < 4; ++i) {
        v[i].x = expf(v[i].x - vmax); v[i].y = expf(v[i].y - vmax);
        v[i].z = expf(v[i].z - vmax); v[i].w = expf(v[i].w - vmax);
        sum += (v[i].x + v[i].y) + (v[i].z + v[i].w);
    }
    #pragma unroll
    for (int off = 32; off > 0; off >>= 1)
        sum += __shfl_xor(sum, off);
    if ((t & 63) == 0) redsum[t >> 6] = sum;
    __syncthreads();
    sum = (redsum[0] + redsum[1]) + (redsum[2] + redsum[3]);
    const float inv = 1.0f / sum;
    #pragma unroll
    for (int i = 0; i < 4; ++i) {
        v[i].x *= inv; v[i].y *= inv; v[i].z *= inv; v[i].w *= inv;
        ((float4*)p)[t + 256 * i] = v[i];
    }
}

template<bool TANH>
__global__ __launch_bounds__(256)
void nt_gemm(const float* __restrict__ A, const float* __restrict__ B,
             float* __restrict__ C, int M, int N, int K,
             long long sA, long long sB, long long sC)
{
    A += (long long)blockIdx.z * sA;
    B += (long long)blockIdx.z * sB;
    C += (long long)blockIdx.z * sC;
    __shared__ __align__(16) float As[BKF][BMF + PADF];
    __shared__ __align__(16) float Bs[BKF][BNF + PADF];
    const int t = threadIdx.x;
    const int m0 = blockIdx.y * BMF, n0 = blockIdx.x * BNF;
    const int tx = t & 15, ty = t >> 4, lr = t >> 2, lk = (t & 3) * 4;
    float acc[4][4] = {};
    for (int kt = 0; kt < K; kt += BKF) {
        {
            float4 v = make_float4(0.f, 0.f, 0.f, 0.f);
            int m = m0 + lr;
            if (m < M) v = *(const float4*)(A + (long long)m * K + kt + lk);
            As[lk+0][lr]=v.x; As[lk+1][lr]=v.y; As[lk+2][lr]=v.z; As[lk+3][lr]=v.w;
        }
        {
            float4 v = make_float4(0.f, 0.f, 0.f, 0.f);
            int n = n0 + lr;
            if (n < N) v = *(const float4*)(B + (long long)n * K + kt + lk);
            Bs[lk+0][lr]=v.x; Bs[lk+1][lr]=v.y; Bs[lk+2][lr]=v.z; Bs[lk+3][lr]=v.w;
        }
        __syncthreads();
        #pragma unroll
        for (int k = 0; k < BKF; ++k) {
            float4 a = *(const float4*)(&As[k][ty * 4]);
            float4 b = *(const float4*)(&Bs[k][tx * 4]);
            float av[4]={a.x,a.y,a.z,a.w}, bv[4]={b.x,b.y,b.z,b.w};
            #pragma unroll
            for (int i = 0; i < 4; ++i)
                #pragma unroll
                for (int j = 0; j < 4; ++j)
                    acc[i][j] = fmaf(av[i], bv[j], acc[i][j]);
        }
        __syncthreads();
    }
    #pragma unroll
    for (int i = 0; i < 4; ++i) {
        int m = m0 + ty * 4 + i;
        if (m < M) {
            float4 r;
            r.x = TANH ? tanhf(acc[i][0]) : acc[i][0];
            r.y = TANH ? tanhf(acc[i][1]) : acc[i][1];
            r.z = TANH ? tanhf(acc[i][2]) : acc[i][2];
            r.w = TANH ? tanhf(acc[i][3]) : acc[i][3];
            *(float4*)(C + (long long)m * N + n0 + tx * 4) = r;
        }
    }
}

__global__ __launch_bounds__(256)
void nn_gemm(const float* __restrict__ A, const float* __restrict__ B,
             float* __restrict__ C, int M, int N, int K,
             long long sA, long long sB, long long sC)
{
    A += (long long)blockIdx.z * sA;
    B += (long long)blockIdx.z * sB;
    C += (long long)blockIdx.z * sC;
    __shared__ __align__(16) float As[BKF][BMF + PADF];
    __shared__ __align__(16) float Bs[BKF][BNF + PADF];
    const int t = threadIdx.x;
    const int m0 = blockIdx.y * BMF, n0 = blockIdx.x * BNF;
    const int tx = t & 15, ty = t >> 4, lr = t >> 2, lk = (t & 3) * 4;
    const int kr = t >> 4, cq = (t & 15) * 4;
    float acc[4][4] = {};
    for (int kt = 0; kt < K; kt += BKF) {
        {
            float4 v = make_float4(0.f, 0.f, 0.f, 0.f);
            int m = m0 + lr;
            if (m < M) v = *(const float4*)(A + (long long)m * K + kt + lk);
            As[lk+0][lr]=v.x; As[lk+1][lr]=v.y; As[lk+2][lr]=v.z; As[lk+3][lr]=v.w;
        }
        {
            float4 v = *(const float4*)(B + (long long)(kt + kr) * N + n0 + cq);
            *(float4*)(&Bs[kr][cq]) = v;
        }
        __syncthreads();
        #pragma unroll
        for (int k = 0; k < BKF; ++k) {
            float4 a = *(const float4*)(&As[k][ty * 4]);
            float4 b = *(const float4*)(&Bs[k][tx * 4]);
            float av[4]={a.x,a.y,a.z,a.w}, bv[4]={b.x,b.y,b.z,b.w};
            #pragma unroll
            for (int i = 0; i < 4; ++i)
                #pragma unroll
                for (int j = 0; j < 4; ++j)
                    acc[i][j] = fmaf(av[i], bv[j], acc[i][j]);
        }
        __syncthreads();
    }
    #pragma unroll
    for (int i = 0; i < 4; ++i) {
        int m = m0 + ty * 4 + i;
        if (m < M)
            *(float4*)(C + (long long)m * N + n0 + tx * 4) =
                make_float4(acc[i][0], acc[i][1], acc[i][2], acc[i][3]);
    }
}

// ===========================================================================
extern "C" void kernel_launch(void* const* d_in, const int* in_sizes, int n_in,
                              void* d_out, int out_size, void* d_ws, size_t ws_size,
                              hipStream_t stream)
{
    const float* code = (const float*)d_in[0];   // (L, H)
    const float* text = (const float*)d_in[1];   // (BS, SEQ, H)
    const float* Wm   = (const float*)d_in[3];   // (H, H)

    float* att  = (float*)d_out;                          // (BS, L, SEQ)
    float* wout = att + (long long)BSZ * NL * SEQN;       // (BS, L, H)

    const long long n_code  = (long long)NL * HD;
    const long long n_proj  = (long long)BSZ * SEQN * HD;
    const long long n_textT = (long long)BSZ * HD * SEQN;
    const long long n_att   = (long long)BSZ * NL * SEQN;
    const size_t need_bytes = (size_t)(n_code + n_proj + n_textT + n_att) * 2;

    if (ws_size < need_bytes) {
        // ---- Tier C: fp32 fallback ----
        float* proj = wout;
        dim3 g1(HD / BNF, (BSZ * SEQN) / BMF, 1);
        hipLaunchKernelGGL((nt_gemm<true>), g1, dim3(256), 0, stream,
                           text, Wm, proj, BSZ * SEQN, HD, HD, 0LL, 0LL, 0LL);
        dim3 g2(SEQN / BNF, (NL + BMF - 1) / BMF, BSZ);
        hipLaunchKernelGGL((nt_gemm<false>), g2, dim3(256), 0, stream,
                           code, proj, att, NL, SEQN, HD,
                           0LL, (long long)SEQN * HD, (long long)NL * SEQN);
        hipLaunchKernelGGL(softmax_rows_f32, dim3(BSZ * NL), dim3(256), 0, stream, att);
        dim3 g4(HD / BNF, (NL + BMF - 1) / BMF, BSZ);
        hipLaunchKernelGGL(nn_gemm, g4, dim3(256), 0, stream,
                           att, text, wout, NL, HD, SEQN,
                           (long long)NL * SEQN, (long long)SEQN * HD, (long long)NL * HD);
        return;
    }

    f16* code_h   = (f16*)d_ws;
    f16* proj_h   = code_h + n_code;
    f16* textT_h  = proj_h + n_proj;
    f16* scores_h = textT_h + n_textT;   // raw scores, then normalized f16 in place

    // 0a) code -> f16
    {
        long long n4 = n_code / 4;
        hipLaunchKernelGGL(cvt_f32_f16, dim3((unsigned)((n4 + 255) / 256)), dim3(256), 0, stream,
                           code, code_h, n4);
    }
    // 0b) text -> textT f16 (BS, HD, SEQN)
    {
        dim3 g(HD / 32, SEQN / 32, BSZ);
        hipLaunchKernelGGL(transpose_f16, g, dim3(256), 0, stream, text, textT_h);
    }
    // 1) proj_h = tanh(text @ W^T) as f16: M=8192, N=768, K=768
    {
        dim3 g(HD / 128, (BSZ * SEQN) / 128, 1);
        hipLaunchKernelGGL((mfma_nt<0, 0, 1>), g, dim3(256), 0, stream,
                           text, Wm, proj_h, BSZ * SEQN, HD, HD, 0LL, 0LL, 0LL, HD, HD);
    }
    // 2) scores_b = code @ proj_b^T -> f16 ws : M=8921, N=4096, K=768
    {
        dim3 g(SEQN / 256, (NL + 255) / 256, BSZ);
        hipLaunchKernelGGL((gemm8p<1>), g, dim3(512), 0, stream,
                           code_h, proj_h, scores_h, NL, SEQN, HD,
                           0LL, (long long)SEQN * HD, (long long)NL * SEQN, HD, HD);
    }
    // 3) softmax: f16 scores -> fp32 att (d_out) + normalized f16 in place
    hipLaunchKernelGGL(softmax_f16, dim3(BSZ * NL), dim3(256), 0, stream, scores_h, att);
    // 4) wout_b = att_b @ textT_b^T : M=8921, N=768, K=4096
    {
        dim3 g(HD / 256, (NL + 255) / 256, BSZ);
        hipLaunchKernelGGL((gemm8p<0>), g, dim3(512), 0, stream,
                           scores_h, textT_h, wout, NL, HD, SEQN,
                           (long long)NL * SEQN, (long long)HD * SEQN, (long long)NL * HD,
                           SEQN, SEQN);
    }
}